// Round 5
// baseline (3220.789 us; speedup 1.0000x reference)
//
#include <hip/hip_runtime.h>

#define N_USER 100000
#define N_ITEM 200000
#define N_NODES 300000
#define LATDIM 64
#define N_EDGE 9600000
#define NCHUNK ((N_NODES + 255) / 256)   // 1172
#define BSHIFT 7
#define RPB 128
#define NBUCK ((N_NODES + RPB - 1) / RPB)  // 2344

__device__ __forceinline__ unsigned int pack_bf16x2(float a, float b) {
    unsigned int ua = __float_as_uint(a);
    unsigned int ub = __float_as_uint(b);
    ua = (ua + 0x7fffu + ((ua >> 16) & 1u)) >> 16;   // RNE
    ub = (ub + 0x7fffu + ((ub >> 16) & 1u)) >> 16;
    return ua | (ub << 16);
}
__device__ __forceinline__ unsigned short f32_to_bf16(float a) {
    unsigned int ua = __float_as_uint(a);
    return (unsigned short)((ua + 0x7fffu + ((ua >> 16) & 1u)) >> 16);
}

// out = concat(u,i) fp32; curp = bf16x2-packed concat(u,i)
__global__ void lgcn_init(const float* __restrict__ u,
                          const float* __restrict__ it,
                          float* __restrict__ out,
                          unsigned int* __restrict__ curp) {
    const size_t total2 = (size_t)N_NODES * 32;   // float2 pairs
    const size_t u2 = (size_t)N_USER * 32;
    const float2* uu = (const float2*)u;
    const float2* ii = (const float2*)it;
    float2* o2 = (float2*)out;
    for (size_t i = (size_t)blockIdx.x * blockDim.x + threadIdx.x; i < total2;
         i += (size_t)gridDim.x * blockDim.x) {
        float2 v = (i < u2) ? uu[i] : ii[i - u2];
        o2[i] = v;
        curp[i] = pack_bf16x2(v.x, v.y);
    }
}

// per-row histogram
__global__ void lgcn_hist(const int* __restrict__ row, int* __restrict__ cnt) {
    int e = blockIdx.x * blockDim.x + threadIdx.x;
    if (e < N_EDGE) atomicAdd(&cnt[row[e]], 1);
}

// per-chunk (256 rows) sums of cnt -> chunkSum
__global__ void lgcn_chunksum(const int* __restrict__ cnt, int* __restrict__ chunkSum) {
    __shared__ int s[256];
    int tid = threadIdx.x;
    int i = blockIdx.x * 256 + tid;
    s[tid] = (i < N_NODES) ? cnt[i] : 0;
    __syncthreads();
    for (int off = 128; off > 0; off >>= 1) {
        if (tid < off) s[tid] += s[tid + off];
        __syncthreads();
    }
    if (tid == 0) chunkSum[blockIdx.x] = s[0];
}

// single-thread exclusive scan of chunkSum; rowStart[N_NODES] = N_EDGE
__global__ void lgcn_chunkscan(int* __restrict__ chunkSum, int* __restrict__ rowStart) {
    if (blockIdx.x == 0 && threadIdx.x == 0) {
        int run = 0;
        for (int j = 0; j < NCHUNK; ++j) {
            int t = chunkSum[j];
            chunkSum[j] = run;
            run += t;
        }
        rowStart[N_NODES] = N_EDGE;
    }
}

// per-chunk exclusive scan of cnt + chunkBase -> rowStart, rowNext
__global__ void lgcn_scan(const int* __restrict__ cnt, const int* __restrict__ chunkBase,
                          int* __restrict__ rowStart, int* __restrict__ rowNext) {
    __shared__ int s[256];
    int tid = threadIdx.x;
    int i = blockIdx.x * 256 + tid;
    int v = (i < N_NODES) ? cnt[i] : 0;
    s[tid] = v;
    __syncthreads();
    for (int off = 1; off < 256; off <<= 1) {
        int t = (tid >= off) ? s[tid - off] : 0;
        __syncthreads();
        s[tid] += t;
        __syncthreads();
    }
    int excl = s[tid] - v + chunkBase[blockIdx.x];
    if (i < N_NODES) {
        rowStart[i] = excl;
        rowNext[i] = excl;
    }
}

// bucket cursors: bcur[b] = rowStart[b*RPB]
__global__ void lgcn_bcur_init(const int* __restrict__ rowStart, int* __restrict__ bcur) {
    int b = blockIdx.x * blockDim.x + threadIdx.x;
    if (b < NBUCK) bcur[b] = rowStart[b * RPB];
}

// stage 1: append edges into bucket regions (dense writes near 2344 cursors)
__global__ void lgcn_append(const int* __restrict__ row, const int* __restrict__ col,
                            const float* __restrict__ vals,
                            int* __restrict__ bcur,
                            unsigned int* __restrict__ recW,
                            unsigned short* __restrict__ recV) {
    int e = blockIdx.x * blockDim.x + threadIdx.x;
    if (e >= N_EDGE) return;
    int r = row[e];
    int pos = atomicAdd(&bcur[r >> BSHIFT], 1);
    recW[pos] = (unsigned int)col[e] | ((unsigned int)(r & (RPB - 1)) << 19);
    recV[pos] = f32_to_bf16(vals[e]);
}

// stage 2: within-bucket scatter to exact CSR positions (writes stay in a
// ~24 KB window per block -> dense lines via L2)
__global__ void lgcn_place2(const int* __restrict__ rowStart,
                            const unsigned int* __restrict__ recW,
                            const unsigned short* __restrict__ recV,
                            int* __restrict__ rowNext,
                            int* __restrict__ colS, unsigned short* __restrict__ valS) {
    int b = blockIdx.x;
    int s = rowStart[b * RPB];
    int rend = (b + 1) * RPB; if (rend > N_NODES) rend = N_NODES;
    int e = rowStart[rend];
    for (int k = s + threadIdx.x; k < e; k += blockDim.x) {
        unsigned int w = recW[k];
        unsigned short v = recV[k];
        int r = b * RPB + (int)(w >> 19);
        int pos = atomicAdd(&rowNext[r], 1);
        colS[pos] = (int)(w & 0x7ffffu);
        valS[pos] = v;
    }
}

// SpMM: one wave per row; halves of the wave process alternating edges.
// lane&31 owns dim pair (2*l32, 2*l32+1). Fused: out[row] += sum (fp32).
__global__ void lgcn_spmm(const int* __restrict__ rowStart,
                          const int* __restrict__ colS,
                          const unsigned short* __restrict__ valS,
                          const unsigned int* __restrict__ cur,
                          unsigned int* __restrict__ nxt,
                          float* __restrict__ out) {
    int wid = blockIdx.x * (blockDim.x >> 6) + (threadIdx.x >> 6);
    if (wid >= N_NODES) return;
    int lane = threadIdx.x & 63;
    int half = lane >> 5;
    int l32 = lane & 31;
    int s = rowStart[wid];
    int e = rowStart[wid + 1];
    float sx = 0.f, sy = 0.f;
    for (int k = s + half; k < e; k += 2) {
        int c = colS[k];
        float v = __uint_as_float(((unsigned int)valS[k]) << 16);
        unsigned int p = cur[(size_t)c * 32 + l32];
        float lo = __uint_as_float(p << 16);
        float hi = __uint_as_float(p & 0xffff0000u);
        sx += v * lo;
        sy += v * hi;
    }
    sx += __shfl_xor(sx, 32);
    sy += __shfl_xor(sy, 32);
    if (half == 0) {
        size_t base = (size_t)wid * 32 + l32;
        nxt[base] = pack_bf16x2(sx, sy);
        float2* o2 = (float2*)out;
        float2 t = o2[base];
        t.x += sx;
        t.y += sy;
        o2[base] = t;
    }
}

extern "C" void kernel_launch(void* const* d_in, const int* in_sizes, int n_in,
                              void* d_out, int out_size, void* d_ws, size_t ws_size,
                              hipStream_t stream) {
    const float* uEmb = (const float*)d_in[0];
    const float* iEmb = (const float*)d_in[1];
    const int* erow = (const int*)d_in[2];
    const int* ecol = (const int*)d_in[3];
    const float* evals = (const float*)d_in[4];
    float* out = (float*)d_out;

    // workspace layout (~136.8 MB, same as round-2 proven footprint).
    // rec{W,V} alias the cur ping-pong region: sort phase finishes before
    // lgcn_init writes curA (place2 consumed rec), and curB is first written
    // by layer-1 spmm, after recV is dead.
    char* p = (char*)d_ws;
    const size_t curBytes = (size_t)N_NODES * 32 * sizeof(unsigned int);  // 38.4 MB
    unsigned int* curA = (unsigned int*)p;
    unsigned int* curB = (unsigned int*)(p + curBytes);
    unsigned int* recW = (unsigned int*)p;                                 // aliases curA
    unsigned short* recV = (unsigned short*)(p + curBytes);                // aliases curB[0..half)
    p += 2 * curBytes;
    int* colS = (int*)p; p += (size_t)N_EDGE * sizeof(int);                // 38.4 MB
    unsigned short* valS = (unsigned short*)p; p += (size_t)N_EDGE * sizeof(unsigned short); // 19.2 MB
    int* rowStart = (int*)p; p += (size_t)(N_NODES + 1) * sizeof(int);
    int* rowNext = (int*)p; p += (size_t)N_NODES * sizeof(int);
    int* chunkSum = (int*)p; p += (size_t)NCHUNK * sizeof(int);
    int* bcur = (int*)p; p += (size_t)NBUCK * sizeof(int);

    const int T = 256;
    const int G_EDGE = (N_EDGE + T - 1) / T;   // 37500
    const int G_SPMM = (N_NODES + 3) / 4;      // 75000 (4 waves/block)

    // ---- sort phase (rec region live) ----
    hipMemsetAsync(rowNext, 0, (size_t)N_NODES * sizeof(int), stream);
    lgcn_hist<<<G_EDGE, T, 0, stream>>>(erow, rowNext);
    lgcn_chunksum<<<NCHUNK, T, 0, stream>>>(rowNext, chunkSum);
    lgcn_chunkscan<<<1, 64, 0, stream>>>(chunkSum, rowStart);
    lgcn_scan<<<NCHUNK, T, 0, stream>>>(rowNext, chunkSum, rowStart, rowNext);
    lgcn_bcur_init<<<(NBUCK + T - 1) / T, T, 0, stream>>>(rowStart, bcur);
    lgcn_append<<<G_EDGE, T, 0, stream>>>(erow, ecol, evals, bcur, recW, recV);
    lgcn_place2<<<NBUCK, T, 0, stream>>>(rowStart, recW, recV, rowNext, colS, valS);

    // ---- dense phase (cur region live) ----
    lgcn_init<<<2048, T, 0, stream>>>(uEmb, iEmb, out, curA);

    unsigned int* cur = curA;
    unsigned int* nxt = curB;
    for (int layer = 0; layer < 3; ++layer) {
        lgcn_spmm<<<G_SPMM, T, 0, stream>>>(rowStart, colS, valS, cur, nxt, out);
        unsigned int* t = cur; cur = nxt; nxt = t;
    }
}

// Round 6
// 2004.379 us; speedup vs baseline: 1.6069x; 1.6069x over previous
//
#include <hip/hip_runtime.h>

#define N_USER 100000
#define N_ITEM 200000
#define N_NODES 300000
#define LATDIM 64
#define N_EDGE 9600000
#define NCHUNK ((N_NODES + 255) / 256)   // 1172
#define BSHIFT 7
#define RPB 128
#define NBUCK ((N_NODES + RPB - 1) / RPB)  // 2344
#define NBLK 1024
#define EPB (N_EDGE / NBLK)                // 9375

__device__ __forceinline__ unsigned int pack_bf16x2(float a, float b) {
    unsigned int ua = __float_as_uint(a);
    unsigned int ub = __float_as_uint(b);
    ua = (ua + 0x7fffu + ((ua >> 16) & 1u)) >> 16;   // RNE
    ub = (ub + 0x7fffu + ((ub >> 16) & 1u)) >> 16;
    return ua | (ub << 16);
}
__device__ __forceinline__ unsigned short f32_to_bf16(float a) {
    unsigned int ua = __float_as_uint(a);
    return (unsigned short)((ua + 0x7fffu + ((ua >> 16) & 1u)) >> 16);
}

// out = concat(u,i) fp32; curp = bf16x2-packed concat(u,i)
__global__ void lgcn_init(const float* __restrict__ u,
                          const float* __restrict__ it,
                          float* __restrict__ out,
                          unsigned int* __restrict__ curp) {
    const size_t total2 = (size_t)N_NODES * 32;
    const size_t u2 = (size_t)N_USER * 32;
    const float2* uu = (const float2*)u;
    const float2* ii = (const float2*)it;
    float2* o2 = (float2*)out;
    for (size_t i = (size_t)blockIdx.x * blockDim.x + threadIdx.x; i < total2;
         i += (size_t)gridDim.x * blockDim.x) {
        float2 v = (i < u2) ? uu[i] : ii[i - u2];
        o2[i] = v;
        curp[i] = pack_bf16x2(v.x, v.y);
    }
}

// per-row histogram (global atomics, 300K counters)
__global__ void lgcn_hist(const int* __restrict__ row, int* __restrict__ cnt) {
    int e = blockIdx.x * blockDim.x + threadIdx.x;
    if (e < N_EDGE) atomicAdd(&cnt[row[e]], 1);
}

// per-chunk (256 rows) sums of cnt -> chunkSum
__global__ void lgcn_chunksum(const int* __restrict__ cnt, int* __restrict__ chunkSum) {
    __shared__ int s[256];
    int tid = threadIdx.x;
    int i = blockIdx.x * 256 + tid;
    s[tid] = (i < N_NODES) ? cnt[i] : 0;
    __syncthreads();
    for (int off = 128; off > 0; off >>= 1) {
        if (tid < off) s[tid] += s[tid + off];
        __syncthreads();
    }
    if (tid == 0) chunkSum[blockIdx.x] = s[0];
}

__global__ void lgcn_chunkscan(int* __restrict__ chunkSum, int* __restrict__ rowStart) {
    if (blockIdx.x == 0 && threadIdx.x == 0) {
        int run = 0;
        for (int j = 0; j < NCHUNK; ++j) {
            int t = chunkSum[j];
            chunkSum[j] = run;
            run += t;
        }
        rowStart[N_NODES] = N_EDGE;
    }
}

__global__ void lgcn_scan(const int* __restrict__ cnt, const int* __restrict__ chunkBase,
                          int* __restrict__ rowStart, int* __restrict__ rowNext) {
    __shared__ int s[256];
    int tid = threadIdx.x;
    int i = blockIdx.x * 256 + tid;
    int v = (i < N_NODES) ? cnt[i] : 0;
    s[tid] = v;
    __syncthreads();
    for (int off = 1; off < 256; off <<= 1) {
        int t = (tid >= off) ? s[tid - off] : 0;
        __syncthreads();
        s[tid] += t;
        __syncthreads();
    }
    int excl = s[tid] - v + chunkBase[blockIdx.x];
    if (i < N_NODES) {
        rowStart[i] = excl;
        rowNext[i] = excl;
    }
}

// bucket base offsets: bcur[b] = rowStart[b*RPB]
__global__ void lgcn_bcur_init(const int* __restrict__ rowStart, int* __restrict__ bcur) {
    int b = blockIdx.x * blockDim.x + threadIdx.x;
    if (b < NBUCK) bcur[b] = rowStart[b * RPB];
}

// partitioned sort stage 1: per-block bucket histogram (LDS int atomics),
// dense block-exclusive writes
__global__ void lgcn_bhist(const int* __restrict__ row, int* __restrict__ histBM) {
    __shared__ int h[NBUCK];
    int blk = blockIdx.x;
    for (int i = threadIdx.x; i < NBUCK; i += blockDim.x) h[i] = 0;
    __syncthreads();
    int s = blk * EPB;
    for (int e = s + threadIdx.x; e < s + EPB; e += blockDim.x)
        atomicAdd(&h[row[e] >> BSHIFT], 1);
    __syncthreads();
    for (int i = threadIdx.x; i < NBUCK; i += blockDim.x)
        histBM[(size_t)blk * NBUCK + i] = h[i];
}

// stage 2: per-bucket exclusive scan over the 1024 blocks
// posT[bucket][blk] = sum_{blk'<blk} histBM[blk'][bucket]
__global__ void lgcn_bposscan(const int* __restrict__ histBM, int* __restrict__ posT) {
    __shared__ int s[256];
    int bucket = blockIdx.x;
    int tid = threadIdx.x;
    int a0 = histBM[(size_t)(4 * tid + 0) * NBUCK + bucket];
    int a1 = histBM[(size_t)(4 * tid + 1) * NBUCK + bucket];
    int a2 = histBM[(size_t)(4 * tid + 2) * NBUCK + bucket];
    int a3 = histBM[(size_t)(4 * tid + 3) * NBUCK + bucket];
    int tot = a0 + a1 + a2 + a3;
    s[tid] = tot;
    __syncthreads();
    for (int o = 1; o < 256; o <<= 1) {
        int t = (tid >= o) ? s[tid - o] : 0;
        __syncthreads();
        s[tid] += t;
        __syncthreads();
    }
    int excl = s[tid] - tot;
    int* dst = &posT[(size_t)bucket * NBLK + 4 * tid];
    dst[0] = excl;
    dst[1] = excl + a0;
    dst[2] = excl + a0 + a1;
    dst[3] = excl + a0 + a1 + a2;
}

// stage 3: placement — block blk owns exact segment bcur[b]+posT[b][blk] per
// bucket; LDS cursors only, ZERO global atomics, block-exclusive writes.
__global__ void lgcn_bplace(const int* __restrict__ row, const int* __restrict__ col,
                            const float* __restrict__ vals,
                            const int* __restrict__ bcur, const int* __restrict__ posT,
                            unsigned int* __restrict__ recW,
                            unsigned short* __restrict__ recV) {
    __shared__ int cursor[NBUCK];
    int blk = blockIdx.x;
    for (int i = threadIdx.x; i < NBUCK; i += blockDim.x)
        cursor[i] = bcur[i] + posT[(size_t)i * NBLK + blk];
    __syncthreads();
    int s = blk * EPB;
    for (int e = s + threadIdx.x; e < s + EPB; e += blockDim.x) {
        int r = row[e];
        int pos = atomicAdd(&cursor[r >> BSHIFT], 1);
        recW[pos] = (unsigned int)col[e] | ((unsigned int)(r & (RPB - 1)) << 19);
        recV[pos] = f32_to_bf16(vals[e]);
    }
}

// stage 4: within-bucket scatter to exact CSR (block-exclusive 24 KB windows)
__global__ void lgcn_place2(const int* __restrict__ rowStart,
                            const unsigned int* __restrict__ recW,
                            const unsigned short* __restrict__ recV,
                            int* __restrict__ rowNext,
                            int* __restrict__ colS, unsigned short* __restrict__ valS) {
    int b = blockIdx.x;
    int s = rowStart[b * RPB];
    int rend = (b + 1) * RPB; if (rend > N_NODES) rend = N_NODES;
    int e = rowStart[rend];
    for (int k = s + threadIdx.x; k < e; k += blockDim.x) {
        unsigned int w = recW[k];
        unsigned short v = recV[k];
        int r = b * RPB + (int)(w >> 19);
        int pos = atomicAdd(&rowNext[r], 1);
        colS[pos] = (int)(w & 0x7ffffu);
        valS[pos] = v;
    }
}

// SpMM: one wave per row; each half-wave pipelines 4 independent gathers.
__global__ void lgcn_spmm(const int* __restrict__ rowStart,
                          const int* __restrict__ colS,
                          const unsigned short* __restrict__ valS,
                          const unsigned int* __restrict__ cur,
                          unsigned int* __restrict__ nxt,
                          float* __restrict__ out) {
    int wid = blockIdx.x * (blockDim.x >> 6) + (threadIdx.x >> 6);
    if (wid >= N_NODES) return;
    int lane = threadIdx.x & 63;
    int half = lane >> 5;
    int l32 = lane & 31;
    int s = rowStart[wid];
    int e = rowStart[wid + 1];
    float sx = 0.f, sy = 0.f, tx = 0.f, ty = 0.f;
    int k = s + half;
    for (; k + 6 < e; k += 8) {
        int c0 = colS[k];
        int c1 = colS[k + 2];
        int c2 = colS[k + 4];
        int c3 = colS[k + 6];
        float v0 = __uint_as_float(((unsigned int)valS[k]) << 16);
        float v1 = __uint_as_float(((unsigned int)valS[k + 2]) << 16);
        float v2 = __uint_as_float(((unsigned int)valS[k + 4]) << 16);
        float v3 = __uint_as_float(((unsigned int)valS[k + 6]) << 16);
        unsigned int p0 = cur[(size_t)c0 * 32 + l32];
        unsigned int p1 = cur[(size_t)c1 * 32 + l32];
        unsigned int p2 = cur[(size_t)c2 * 32 + l32];
        unsigned int p3 = cur[(size_t)c3 * 32 + l32];
        sx += v0 * __uint_as_float(p0 << 16);
        sy += v0 * __uint_as_float(p0 & 0xffff0000u);
        tx += v1 * __uint_as_float(p1 << 16);
        ty += v1 * __uint_as_float(p1 & 0xffff0000u);
        sx += v2 * __uint_as_float(p2 << 16);
        sy += v2 * __uint_as_float(p2 & 0xffff0000u);
        tx += v3 * __uint_as_float(p3 << 16);
        ty += v3 * __uint_as_float(p3 & 0xffff0000u);
    }
    for (; k < e; k += 2) {
        int c = colS[k];
        float v = __uint_as_float(((unsigned int)valS[k]) << 16);
        unsigned int p = cur[(size_t)c * 32 + l32];
        sx += v * __uint_as_float(p << 16);
        sy += v * __uint_as_float(p & 0xffff0000u);
    }
    sx += tx; sy += ty;
    sx += __shfl_xor(sx, 32);
    sy += __shfl_xor(sy, 32);
    if (half == 0) {
        size_t base = (size_t)wid * 32 + l32;
        nxt[base] = pack_bf16x2(sx, sy);
        float2* o2 = (float2*)out;
        float2 t = o2[base];
        t.x += sx;
        t.y += sy;
        o2[base] = t;
    }
}

extern "C" void kernel_launch(void* const* d_in, const int* in_sizes, int n_in,
                              void* d_out, int out_size, void* d_ws, size_t ws_size,
                              hipStream_t stream) {
    const float* uEmb = (const float*)d_in[0];
    const float* iEmb = (const float*)d_in[1];
    const int* erow = (const int*)d_in[2];
    const int* ecol = (const int*)d_in[3];
    const float* evals = (const float*)d_in[4];
    float* out = (float*)d_out;

    // workspace (~136.8 MB, proven footprint). Aliasing (disjoint lifetimes):
    //   recW  <- curA region    (rec dead before lgcn_init writes curA)
    //   recV  <- curB region    (dead before layer-1 spmm writes curB)
    //   histBM, posT <- colS region (dead before place2 writes colS)
    char* p = (char*)d_ws;
    const size_t curBytes = (size_t)N_NODES * 32 * sizeof(unsigned int);  // 38.4 MB
    unsigned int* curA = (unsigned int*)p;
    unsigned int* curB = (unsigned int*)(p + curBytes);
    unsigned int* recW = (unsigned int*)p;
    unsigned short* recV = (unsigned short*)(p + curBytes);
    p += 2 * curBytes;
    int* colS = (int*)p;
    int* histBM = (int*)p;                                                 // 9.6 MB
    int* posT = (int*)(p + (size_t)NBLK * NBUCK * sizeof(int));            // 9.6 MB
    p += (size_t)N_EDGE * sizeof(int);                                     // 38.4 MB
    unsigned short* valS = (unsigned short*)p; p += (size_t)N_EDGE * sizeof(unsigned short);
    int* rowStart = (int*)p; p += (size_t)(N_NODES + 1) * sizeof(int);
    int* rowNext = (int*)p; p += (size_t)N_NODES * sizeof(int);
    int* chunkSum = (int*)p; p += (size_t)NCHUNK * sizeof(int);
    int* bcur = (int*)p; p += (size_t)NBUCK * sizeof(int);

    const int T = 256;
    const int G_EDGE = (N_EDGE + T - 1) / T;
    const int G_SPMM = (N_NODES + 3) / 4;

    // ---- CSR offsets ----
    hipMemsetAsync(rowNext, 0, (size_t)N_NODES * sizeof(int), stream);
    lgcn_hist<<<G_EDGE, T, 0, stream>>>(erow, rowNext);
    lgcn_chunksum<<<NCHUNK, T, 0, stream>>>(rowNext, chunkSum);
    lgcn_chunkscan<<<1, 64, 0, stream>>>(chunkSum, rowStart);
    lgcn_scan<<<NCHUNK, T, 0, stream>>>(rowNext, chunkSum, rowStart, rowNext);
    lgcn_bcur_init<<<(NBUCK + T - 1) / T, T, 0, stream>>>(rowStart, bcur);

    // ---- partitioned counting sort (no global atomics) ----
    lgcn_bhist<<<NBLK, T, 0, stream>>>(erow, histBM);
    lgcn_bposscan<<<NBUCK, T, 0, stream>>>(histBM, posT);
    lgcn_bplace<<<NBLK, T, 0, stream>>>(erow, ecol, evals, bcur, posT, recW, recV);
    lgcn_place2<<<NBUCK, T, 0, stream>>>(rowStart, recW, recV, rowNext, colS, valS);

    // ---- dense phase ----
    lgcn_init<<<2048, T, 0, stream>>>(uEmb, iEmb, out, curA);

    unsigned int* cur = curA;
    unsigned int* nxt = curB;
    for (int layer = 0; layer < 3; ++layer) {
        lgcn_spmm<<<G_SPMM, T, 0, stream>>>(rowStart, colS, valS, cur, nxt, out);
        unsigned int* t = cur; cur = nxt; nxt = t;
    }
}

// Round 8
// 1363.054 us; speedup vs baseline: 2.3629x; 1.4705x over previous
//
#include <hip/hip_runtime.h>

#define N_USER 100000
#define N_ITEM 200000
#define N_NODES 300000
#define LATDIM 64
#define N_EDGE 9600000
#define BSHIFT 7
#define RPB 128
#define NBUCK ((N_NODES + RPB - 1) / RPB)  // 2344
#define NBLK 256
#define EPB (N_EDGE / NBLK)                // 37500

__device__ __forceinline__ unsigned int pack_bf16x2(float a, float b) {
    unsigned int ua = __float_as_uint(a);
    unsigned int ub = __float_as_uint(b);
    ua = (ua + 0x7fffu + ((ua >> 16) & 1u)) >> 16;   // RNE
    ub = (ub + 0x7fffu + ((ub >> 16) & 1u)) >> 16;
    return ua | (ub << 16);
}
__device__ __forceinline__ unsigned short f32_to_bf16(float a) {
    unsigned int ua = __float_as_uint(a);
    return (unsigned short)((ua + 0x7fffu + ((ua >> 16) & 1u)) >> 16);
}

// out = concat(u,i) fp32; curp = bf16x2-packed concat(u,i)
__global__ void lgcn_init(const float* __restrict__ u,
                          const float* __restrict__ it,
                          float* __restrict__ out,
                          unsigned int* __restrict__ curp) {
    const size_t total2 = (size_t)N_NODES * 32;
    const size_t u2 = (size_t)N_USER * 32;
    const float2* uu = (const float2*)u;
    const float2* ii = (const float2*)it;
    float2* o2 = (float2*)out;
    for (size_t i = (size_t)blockIdx.x * blockDim.x + threadIdx.x; i < total2;
         i += (size_t)gridDim.x * blockDim.x) {
        float2 v = (i < u2) ? uu[i] : ii[i - u2];
        o2[i] = v;
        curp[i] = pack_bf16x2(v.x, v.y);
    }
}

// stage 1: per-block bucket histogram (LDS atomics, dense block-major writes)
__global__ void lgcn_bhist(const int* __restrict__ row, int* __restrict__ histBM) {
    __shared__ int h[NBUCK];
    int blk = blockIdx.x;
    for (int i = threadIdx.x; i < NBUCK; i += blockDim.x) h[i] = 0;
    __syncthreads();
    int s = blk * EPB;
    for (int e = s + threadIdx.x; e < s + EPB; e += blockDim.x)
        atomicAdd(&h[row[e] >> BSHIFT], 1);
    __syncthreads();
    for (int i = threadIdx.x; i < NBUCK; i += blockDim.x)
        histBM[(size_t)blk * NBUCK + i] = h[i];
}

// stage 2: per-bucket exclusive scan over the NBLK blocks; emit bucket totals
__global__ void lgcn_bposscan(const int* __restrict__ histBM,
                              int* __restrict__ posT,
                              int* __restrict__ bucketTotal) {
    __shared__ int s[NBLK];
    int bucket = blockIdx.x;
    int tid = threadIdx.x;          // blockDim.x == NBLK
    int v = histBM[(size_t)tid * NBUCK + bucket];
    s[tid] = v;
    __syncthreads();
    for (int o = 1; o < NBLK; o <<= 1) {
        int t = (tid >= o) ? s[tid - o] : 0;
        __syncthreads();
        s[tid] += t;
        __syncthreads();
    }
    posT[(size_t)bucket * NBLK + tid] = s[tid] - v;
    if (tid == NBLK - 1) bucketTotal[bucket] = s[tid];
}

// stage 3: exclusive scan of bucket totals -> bcur[NBUCK+1]; sentinels
__global__ void lgcn_bscan(const int* __restrict__ bucketTotal,
                           int* __restrict__ bcur, int* __restrict__ rowStart) {
    __shared__ int tsum[1024];
    int tid = threadIdx.x;
    int base = tid * 3;
    int a0 = 0, a1 = 0, a2 = 0;
    if (base < NBUCK) a0 = bucketTotal[base];
    if (base + 1 < NBUCK) a1 = bucketTotal[base + 1];
    if (base + 2 < NBUCK) a2 = bucketTotal[base + 2];
    tsum[tid] = a0 + a1 + a2;
    __syncthreads();
    for (int o = 1; o < 1024; o <<= 1) {
        int t = (tid >= o) ? tsum[tid - o] : 0;
        __syncthreads();
        tsum[tid] += t;
        __syncthreads();
    }
    int excl = (tid > 0) ? tsum[tid - 1] : 0;
    if (base < NBUCK) bcur[base] = excl;
    if (base + 1 < NBUCK) bcur[base + 1] = excl + a0;
    if (base + 2 < NBUCK) bcur[base + 2] = excl + a0 + a1;
    if (tid == 1023) {
        bcur[NBUCK] = N_EDGE;
        rowStart[N_NODES] = N_EDGE;
    }
}

// stage 4: placement into bucket-grouped order; 8B records, zero global
// atomics, per-(block,bucket) segments = 16 recs = 128 B (>= 2 lines)
__global__ void lgcn_bplace(const int* __restrict__ row, const int* __restrict__ col,
                            const float* __restrict__ vals,
                            const int* __restrict__ bcur, const int* __restrict__ posT,
                            uint2* __restrict__ recs) {
    __shared__ int cursor[NBUCK];
    int blk = blockIdx.x;
    for (int i = threadIdx.x; i < NBUCK; i += blockDim.x)
        cursor[i] = bcur[i] + posT[(size_t)i * NBLK + blk];
    __syncthreads();
    int s = blk * EPB;
    for (int e = s + threadIdx.x; e < s + EPB; e += blockDim.x) {
        int r = row[e];
        int pos = atomicAdd(&cursor[r >> BSHIFT], 1);
        uint2 rec;
        rec.x = (unsigned int)col[e] | ((unsigned int)(r & (RPB - 1)) << 19);
        rec.y = __float_as_uint(vals[e]);
        recs[pos] = rec;
    }
}

// stage 5: per-bucket row histogram + LDS scan -> rowStart; scatter to exact
// CSR (block-exclusive ~24 KB windows). No global hist/scan passes needed.
__global__ void lgcn_csr(const int* __restrict__ bcur,
                         const uint2* __restrict__ recs,
                         int* __restrict__ rowStart,
                         int* __restrict__ colS, unsigned short* __restrict__ valS) {
    __shared__ int rcnt[RPB];
    __shared__ int sc[RPB];
    __shared__ int rcur[RPB];
    int b = blockIdx.x, tid = threadIdx.x;
    int s = bcur[b], e = bcur[b + 1];
    for (int i = tid; i < RPB; i += blockDim.x) rcnt[i] = 0;
    __syncthreads();
    for (int k = s + tid; k < e; k += blockDim.x)
        atomicAdd(&rcnt[recs[k].x >> 19], 1);
    __syncthreads();
    int v = (tid < RPB) ? rcnt[tid] : 0;
    if (tid < RPB) sc[tid] = v;
    __syncthreads();
    for (int o = 1; o < RPB; o <<= 1) {
        int t = (tid < RPB && tid >= o) ? sc[tid - o] : 0;
        __syncthreads();
        if (tid < RPB) sc[tid] += t;
        __syncthreads();
    }
    if (tid < RPB) {
        int excl = s + sc[tid] - v;
        rcur[tid] = excl;
        int r = b * RPB + tid;
        if (r < N_NODES) rowStart[r] = excl;
    }
    __syncthreads();
    for (int k = s + tid; k < e; k += blockDim.x) {
        uint2 rec = recs[k];
        int rl = (int)(rec.x >> 19);
        int pos = atomicAdd(&rcur[rl], 1);
        colS[pos] = (int)(rec.x & 0x7ffffu);
        valS[pos] = f32_to_bf16(__uint_as_float(rec.y));
    }
}

// SpMM: one wave per row; each half-wave pipelines 4 independent gathers.
__global__ void lgcn_spmm(const int* __restrict__ rowStart,
                          const int* __restrict__ colS,
                          const unsigned short* __restrict__ valS,
                          const unsigned int* __restrict__ cur,
                          unsigned int* __restrict__ nxt,
                          float* __restrict__ out) {
    int wid = blockIdx.x * (blockDim.x >> 6) + (threadIdx.x >> 6);
    if (wid >= N_NODES) return;
    int lane = threadIdx.x & 63;
    int half = lane >> 5;
    int l32 = lane & 31;
    int s = rowStart[wid];
    int e = rowStart[wid + 1];
    float sx = 0.f, sy = 0.f, tx = 0.f, ty = 0.f;
    int k = s + half;
    for (; k + 6 < e; k += 8) {
        int c0 = colS[k];
        int c1 = colS[k + 2];
        int c2 = colS[k + 4];
        int c3 = colS[k + 6];
        float v0 = __uint_as_float(((unsigned int)valS[k]) << 16);
        float v1 = __uint_as_float(((unsigned int)valS[k + 2]) << 16);
        float v2 = __uint_as_float(((unsigned int)valS[k + 4]) << 16);
        float v3 = __uint_as_float(((unsigned int)valS[k + 6]) << 16);
        unsigned int p0 = cur[(size_t)c0 * 32 + l32];
        unsigned int p1 = cur[(size_t)c1 * 32 + l32];
        unsigned int p2 = cur[(size_t)c2 * 32 + l32];
        unsigned int p3 = cur[(size_t)c3 * 32 + l32];
        sx += v0 * __uint_as_float(p0 << 16);
        sy += v0 * __uint_as_float(p0 & 0xffff0000u);
        tx += v1 * __uint_as_float(p1 << 16);
        ty += v1 * __uint_as_float(p1 & 0xffff0000u);
        sx += v2 * __uint_as_float(p2 << 16);
        sy += v2 * __uint_as_float(p2 & 0xffff0000u);
        tx += v3 * __uint_as_float(p3 << 16);
        ty += v3 * __uint_as_float(p3 & 0xffff0000u);
    }
    for (; k < e; k += 2) {
        int c = colS[k];
        float v = __uint_as_float(((unsigned int)valS[k]) << 16);
        unsigned int p = cur[(size_t)c * 32 + l32];
        sx += v * __uint_as_float(p << 16);
        sy += v * __uint_as_float(p & 0xffff0000u);
    }
    sx += tx; sy += ty;
    sx += __shfl_xor(sx, 32);
    sy += __shfl_xor(sy, 32);
    if (half == 0) {
        size_t base = (size_t)wid * 32 + l32;
        nxt[base] = pack_bf16x2(sx, sy);
        float2* o2 = (float2*)out;
        float2 t = o2[base];
        t.x += sx;
        t.y += sy;
        o2[base] = t;
    }
}

extern "C" void kernel_launch(void* const* d_in, const int* in_sizes, int n_in,
                              void* d_out, int out_size, void* d_ws, size_t ws_size,
                              hipStream_t stream) {
    const float* uEmb = (const float*)d_in[0];
    const float* iEmb = (const float*)d_in[1];
    const int* erow = (const int*)d_in[2];
    const int* ecol = (const int*)d_in[3];
    const float* evals = (const float*)d_in[4];
    float* out = (float*)d_out;

    // workspace (~135.6 MB). Aliasing (disjoint lifetimes):
    //   recs (76.8 MB)      <- curA+curB region (recs dead before lgcn_init)
    //   histBM, posT (4.8M) <- front of colS (dead before lgcn_csr writes colS)
    char* p = (char*)d_ws;
    const size_t curBytes = (size_t)N_NODES * 32 * sizeof(unsigned int);  // 38.4 MB
    unsigned int* curA = (unsigned int*)p;
    unsigned int* curB = (unsigned int*)(p + curBytes);
    uint2* recs = (uint2*)p;
    p += 2 * curBytes;
    int* colS = (int*)p;
    int* histBM = (int*)p;                                                 // 2.4 MB
    int* posT = (int*)(p + (size_t)NBLK * NBUCK * sizeof(int));            // 2.4 MB
    p += (size_t)N_EDGE * sizeof(int);                                     // 38.4 MB
    unsigned short* valS = (unsigned short*)p; p += (size_t)N_EDGE * sizeof(unsigned short);
    int* rowStart = (int*)p; p += (size_t)(N_NODES + 1) * sizeof(int);
    int* bcur = (int*)p; p += (size_t)(NBUCK + 1) * sizeof(int);
    int* bucketTotal = (int*)p; p += (size_t)NBUCK * sizeof(int);

    const int T = 256;
    const int G_SPMM = (N_NODES + 3) / 4;   // 4 waves/block

    // ---- partitioned counting sort -> CSR (no global atomics, no memsets) ----
    lgcn_bhist<<<NBLK, T, 0, stream>>>(erow, histBM);
    lgcn_bposscan<<<NBUCK, NBLK, 0, stream>>>(histBM, posT, bucketTotal);
    lgcn_bscan<<<1, 1024, 0, stream>>>(bucketTotal, bcur, rowStart);
    lgcn_bplace<<<NBLK, T, 0, stream>>>(erow, ecol, evals, bcur, posT, recs);
    lgcn_csr<<<NBUCK, T, 0, stream>>>(bcur, recs, rowStart, colS, valS);

    // ---- dense phase ----
    lgcn_init<<<2048, T, 0, stream>>>(uEmb, iEmb, out, curA);

    unsigned int* cur = curA;
    unsigned int* nxt = curB;
    for (int layer = 0; layer < 3; ++layer) {
        lgcn_spmm<<<G_SPMM, T, 0, stream>>>(rowStart, colS, valS, cur, nxt, out);
        unsigned int* t = cur; cur = nxt; nxt = t;
    }
}

// Round 10
// 1246.586 us; speedup vs baseline: 2.5837x; 1.0934x over previous
//
#include <hip/hip_runtime.h>

#define N_USER 100000
#define N_ITEM 200000
#define N_NODES 300000
#define LATDIM 64
#define N_EDGE 9600000
#define BSHIFT 9
#define RPB 512
#define NBUCK ((N_NODES + RPB - 1) / RPB)  // 586
#define NBLK 1024
#define EPB (N_EDGE / NBLK)                // 9375

__device__ __forceinline__ unsigned int pack_bf16x2(float a, float b) {
    unsigned int ua = __float_as_uint(a);
    unsigned int ub = __float_as_uint(b);
    ua = (ua + 0x7fffu + ((ua >> 16) & 1u)) >> 16;   // RNE
    ub = (ub + 0x7fffu + ((ub >> 16) & 1u)) >> 16;
    return ua | (ub << 16);
}
__device__ __forceinline__ unsigned short f32_to_bf16(float a) {
    unsigned int ua = __float_as_uint(a);
    return (unsigned short)((ua + 0x7fffu + ((ua >> 16) & 1u)) >> 16);
}

// out = concat(u,i) fp32; curp = bf16x2-packed concat(u,i)
__global__ void lgcn_init(const float* __restrict__ u,
                          const float* __restrict__ it,
                          float* __restrict__ out,
                          unsigned int* __restrict__ curp) {
    const size_t total2 = (size_t)N_NODES * 32;
    const size_t u2 = (size_t)N_USER * 32;
    const float2* uu = (const float2*)u;
    const float2* ii = (const float2*)it;
    float2* o2 = (float2*)out;
    for (size_t i = (size_t)blockIdx.x * blockDim.x + threadIdx.x; i < total2;
         i += (size_t)gridDim.x * blockDim.x) {
        float2 v = (i < u2) ? uu[i] : ii[i - u2];
        o2[i] = v;
        curp[i] = pack_bf16x2(v.x, v.y);
    }
}

// stage 1: per-block bucket histogram (LDS atomics, dense block-major writes)
__global__ void lgcn_bhist(const int* __restrict__ row, int* __restrict__ histBM) {
    __shared__ int h[NBUCK];
    int blk = blockIdx.x;
    for (int i = threadIdx.x; i < NBUCK; i += blockDim.x) h[i] = 0;
    __syncthreads();
    int s = blk * EPB;
    for (int e = s + threadIdx.x; e < s + EPB; e += blockDim.x)
        atomicAdd(&h[row[e] >> BSHIFT], 1);
    __syncthreads();
    for (int i = threadIdx.x; i < NBUCK; i += blockDim.x)
        histBM[(size_t)blk * NBUCK + i] = h[i];
}

// stage 2: per-bucket exclusive scan over the NBLK blocks; emit bucket totals
__global__ void lgcn_bposscan(const int* __restrict__ histBM,
                              int* __restrict__ posT,
                              int* __restrict__ bucketTotal) {
    __shared__ int s[NBLK];
    int bucket = blockIdx.x;
    int tid = threadIdx.x;          // blockDim.x == NBLK == 1024
    int v = histBM[(size_t)tid * NBUCK + bucket];
    s[tid] = v;
    __syncthreads();
    for (int o = 1; o < NBLK; o <<= 1) {
        int t = (tid >= o) ? s[tid - o] : 0;
        __syncthreads();
        s[tid] += t;
        __syncthreads();
    }
    posT[(size_t)bucket * NBLK + tid] = s[tid] - v;
    if (tid == NBLK - 1) bucketTotal[bucket] = s[tid];
}

// stage 3: exclusive scan of bucket totals -> bcur[NBUCK+1]; sentinels
__global__ void lgcn_bscan(const int* __restrict__ bucketTotal,
                           int* __restrict__ bcur, int* __restrict__ rowStart) {
    __shared__ int tsum[1024];
    int tid = threadIdx.x;
    int v = (tid < NBUCK) ? bucketTotal[tid] : 0;
    tsum[tid] = v;
    __syncthreads();
    for (int o = 1; o < 1024; o <<= 1) {
        int t = (tid >= o) ? tsum[tid - o] : 0;
        __syncthreads();
        tsum[tid] += t;
        __syncthreads();
    }
    if (tid < NBUCK) bcur[tid] = tsum[tid] - v;
    if (tid == 0) {
        bcur[NBUCK] = N_EDGE;
        rowStart[N_NODES] = N_EDGE;
    }
}

// stage 4: placement into bucket-grouped order; 8B records, zero global
// atomics, per-(block,bucket) segments avg 16 recs = 128 B (>= 2 lines)
__global__ void lgcn_bplace(const int* __restrict__ row, const int* __restrict__ col,
                            const float* __restrict__ vals,
                            const int* __restrict__ bcur, const int* __restrict__ posT,
                            uint2* __restrict__ recs) {
    __shared__ int cursor[NBUCK];
    int blk = blockIdx.x;
    for (int i = threadIdx.x; i < NBUCK; i += blockDim.x)
        cursor[i] = bcur[i] + posT[(size_t)i * NBLK + blk];
    __syncthreads();
    int s = blk * EPB;
    for (int e = s + threadIdx.x; e < s + EPB; e += blockDim.x) {
        int r = row[e];
        int pos = atomicAdd(&cursor[r >> BSHIFT], 1);
        uint2 rec;
        rec.x = (unsigned int)col[e] | ((unsigned int)(r & (RPB - 1)) << 19);
        rec.y = __float_as_uint(vals[e]);
        recs[pos] = rec;
    }
}

// stage 5: per-bucket row histogram + LDS scan -> rowStart; scatter to exact
// CSR (block-exclusive ~96 KB windows). blockDim == RPB == 512.
__global__ void lgcn_csr(const int* __restrict__ bcur,
                         const uint2* __restrict__ recs,
                         int* __restrict__ rowStart,
                         int* __restrict__ colS, unsigned short* __restrict__ valS) {
    __shared__ int rcnt[RPB];
    __shared__ int sc[RPB];
    __shared__ int rcur[RPB];
    int b = blockIdx.x, tid = threadIdx.x;
    int s = bcur[b], e = bcur[b + 1];
    rcnt[tid] = 0;
    __syncthreads();
    for (int k = s + tid; k < e; k += blockDim.x)
        atomicAdd(&rcnt[recs[k].x >> 19], 1);
    __syncthreads();
    int v = rcnt[tid];
    sc[tid] = v;
    __syncthreads();
    for (int o = 1; o < RPB; o <<= 1) {
        int t = (tid >= o) ? sc[tid - o] : 0;
        __syncthreads();
        sc[tid] += t;
        __syncthreads();
    }
    {
        int excl = s + sc[tid] - v;
        rcur[tid] = excl;
        int r = b * RPB + tid;
        if (r < N_NODES) rowStart[r] = excl;
    }
    __syncthreads();
    for (int k = s + tid; k < e; k += blockDim.x) {
        uint2 rec = recs[k];
        int rl = (int)(rec.x >> 19);
        int pos = atomicAdd(&rcur[rl], 1);
        colS[pos] = (int)(rec.x & 0x7ffffu);
        valS[pos] = f32_to_bf16(__uint_as_float(rec.y));
    }
}

// SpMM: one wave per row; each half-wave keeps 8 independent gathers in flight.
__global__ void lgcn_spmm(const int* __restrict__ rowStart,
                          const int* __restrict__ colS,
                          const unsigned short* __restrict__ valS,
                          const unsigned int* __restrict__ cur,
                          unsigned int* __restrict__ nxt,
                          float* __restrict__ out) {
    int wid = blockIdx.x * (blockDim.x >> 6) + (threadIdx.x >> 6);
    if (wid >= N_NODES) return;
    int lane = threadIdx.x & 63;
    int half = lane >> 5;
    int l32 = lane & 31;
    int s = rowStart[wid];
    int e = rowStart[wid + 1];
    float sx = 0.f, sy = 0.f, tx = 0.f, ty = 0.f;
    int k = s + half;
    for (; k + 14 < e; k += 16) {
        int c0 = colS[k];
        int c1 = colS[k + 2];
        int c2 = colS[k + 4];
        int c3 = colS[k + 6];
        int c4 = colS[k + 8];
        int c5 = colS[k + 10];
        int c6 = colS[k + 12];
        int c7 = colS[k + 14];
        unsigned int p0 = cur[(size_t)c0 * 32 + l32];
        unsigned int p1 = cur[(size_t)c1 * 32 + l32];
        unsigned int p2 = cur[(size_t)c2 * 32 + l32];
        unsigned int p3 = cur[(size_t)c3 * 32 + l32];
        unsigned int p4 = cur[(size_t)c4 * 32 + l32];
        unsigned int p5 = cur[(size_t)c5 * 32 + l32];
        unsigned int p6 = cur[(size_t)c6 * 32 + l32];
        unsigned int p7 = cur[(size_t)c7 * 32 + l32];
        float v0 = __uint_as_float(((unsigned int)valS[k]) << 16);
        float v1 = __uint_as_float(((unsigned int)valS[k + 2]) << 16);
        float v2 = __uint_as_float(((unsigned int)valS[k + 4]) << 16);
        float v3 = __uint_as_float(((unsigned int)valS[k + 6]) << 16);
        float v4 = __uint_as_float(((unsigned int)valS[k + 8]) << 16);
        float v5 = __uint_as_float(((unsigned int)valS[k + 10]) << 16);
        float v6 = __uint_as_float(((unsigned int)valS[k + 12]) << 16);
        float v7 = __uint_as_float(((unsigned int)valS[k + 14]) << 16);
        sx += v0 * __uint_as_float(p0 << 16);
        sy += v0 * __uint_as_float(p0 & 0xffff0000u);
        tx += v1 * __uint_as_float(p1 << 16);
        ty += v1 * __uint_as_float(p1 & 0xffff0000u);
        sx += v2 * __uint_as_float(p2 << 16);
        sy += v2 * __uint_as_float(p2 & 0xffff0000u);
        tx += v3 * __uint_as_float(p3 << 16);
        ty += v3 * __uint_as_float(p3 & 0xffff0000u);
        sx += v4 * __uint_as_float(p4 << 16);
        sy += v4 * __uint_as_float(p4 & 0xffff0000u);
        tx += v5 * __uint_as_float(p5 << 16);
        ty += v5 * __uint_as_float(p5 & 0xffff0000u);
        sx += v6 * __uint_as_float(p6 << 16);
        sy += v6 * __uint_as_float(p6 & 0xffff0000u);
        tx += v7 * __uint_as_float(p7 << 16);
        ty += v7 * __uint_as_float(p7 & 0xffff0000u);
    }
    for (; k + 6 < e; k += 8) {
        int c0 = colS[k];
        int c1 = colS[k + 2];
        int c2 = colS[k + 4];
        int c3 = colS[k + 6];
        float v0 = __uint_as_float(((unsigned int)valS[k]) << 16);
        float v1 = __uint_as_float(((unsigned int)valS[k + 2]) << 16);
        float v2 = __uint_as_float(((unsigned int)valS[k + 4]) << 16);
        float v3 = __uint_as_float(((unsigned int)valS[k + 6]) << 16);
        unsigned int p0 = cur[(size_t)c0 * 32 + l32];
        unsigned int p1 = cur[(size_t)c1 * 32 + l32];
        unsigned int p2 = cur[(size_t)c2 * 32 + l32];
        unsigned int p3 = cur[(size_t)c3 * 32 + l32];
        sx += v0 * __uint_as_float(p0 << 16);
        sy += v0 * __uint_as_float(p0 & 0xffff0000u);
        tx += v1 * __uint_as_float(p1 << 16);
        ty += v1 * __uint_as_float(p1 & 0xffff0000u);
        sx += v2 * __uint_as_float(p2 << 16);
        sy += v2 * __uint_as_float(p2 & 0xffff0000u);
        tx += v3 * __uint_as_float(p3 << 16);
        ty += v3 * __uint_as_float(p3 & 0xffff0000u);
    }
    for (; k < e; k += 2) {
        int c = colS[k];
        float v = __uint_as_float(((unsigned int)valS[k]) << 16);
        unsigned int p = cur[(size_t)c * 32 + l32];
        sx += v * __uint_as_float(p << 16);
        sy += v * __uint_as_float(p & 0xffff0000u);
    }
    sx += tx; sy += ty;
    sx += __shfl_xor(sx, 32);
    sy += __shfl_xor(sy, 32);
    if (half == 0) {
        size_t base = (size_t)wid * 32 + l32;
        nxt[base] = pack_bf16x2(sx, sy);
        float2* o2 = (float2*)out;
        float2 t = o2[base];
        t.x += sx;
        t.y += sy;
        o2[base] = t;
    }
}

extern "C" void kernel_launch(void* const* d_in, const int* in_sizes, int n_in,
                              void* d_out, int out_size, void* d_ws, size_t ws_size,
                              hipStream_t stream) {
    const float* uEmb = (const float*)d_in[0];
    const float* iEmb = (const float*)d_in[1];
    const int* erow = (const int*)d_in[2];
    const int* ecol = (const int*)d_in[3];
    const float* evals = (const float*)d_in[4];
    float* out = (float*)d_out;

    // workspace (~135.6 MB). Aliasing (disjoint lifetimes):
    //   recs (76.8 MB)      <- curA+curB region (recs dead before lgcn_init)
    //   histBM, posT (4.8M) <- front of colS (dead before lgcn_csr writes colS)
    char* p = (char*)d_ws;
    const size_t curBytes = (size_t)N_NODES * 32 * sizeof(unsigned int);  // 38.4 MB
    unsigned int* curA = (unsigned int*)p;
    unsigned int* curB = (unsigned int*)(p + curBytes);
    uint2* recs = (uint2*)p;
    p += 2 * curBytes;
    int* colS = (int*)p;
    int* histBM = (int*)p;                                                 // 2.4 MB
    int* posT = (int*)(p + (size_t)NBLK * NBUCK * sizeof(int));            // 2.4 MB
    p += (size_t)N_EDGE * sizeof(int);                                     // 38.4 MB
    unsigned short* valS = (unsigned short*)p; p += (size_t)N_EDGE * sizeof(unsigned short);
    int* rowStart = (int*)p; p += (size_t)(N_NODES + 1) * sizeof(int);
    int* bcur = (int*)p; p += (size_t)(NBUCK + 1) * sizeof(int);
    int* bucketTotal = (int*)p; p += (size_t)NBUCK * sizeof(int);

    const int T = 256;
    const int G_SPMM = (N_NODES + 3) / 4;   // 4 waves/block

    // ---- partitioned counting sort -> CSR (no global atomics, no memsets) ----
    lgcn_bhist<<<NBLK, T, 0, stream>>>(erow, histBM);
    lgcn_bposscan<<<NBUCK, NBLK, 0, stream>>>(histBM, posT, bucketTotal);
    lgcn_bscan<<<1, 1024, 0, stream>>>(bucketTotal, bcur, rowStart);
    lgcn_bplace<<<NBLK, T, 0, stream>>>(erow, ecol, evals, bcur, posT, recs);
    lgcn_csr<<<NBUCK, RPB, 0, stream>>>(bcur, recs, rowStart, colS, valS);

    // ---- dense phase ----
    lgcn_init<<<2048, T, 0, stream>>>(uEmb, iEmb, out, curA);

    unsigned int* cur = curA;
    unsigned int* nxt = curB;
    for (int layer = 0; layer < 3; ++layer) {
        lgcn_spmm<<<G_SPMM, T, 0, stream>>>(rowStart, colS, valS, cur, nxt, out);
        unsigned int* t = cur; cur = nxt; nxt = t;
    }
}